// Round 1
// baseline (125.130 us; speedup 1.0000x reference)
//
#include <hip/hip_runtime.h>
#include <hip/hip_bf16.h>

#define N_TOT 8192
#define B_HALF 4096
#define D_DIM 256
#define BM 128
#define BN 128
#define CHUNK 1024
#define NRT (N_TOT / BM)     // 64 row tiles
#define NCS (N_TOT / CHUNK)  // 8 col chunks

typedef __attribute__((ext_vector_type(8))) short short8;
typedef __attribute__((ext_vector_type(8))) unsigned short ushort8;
typedef __attribute__((ext_vector_type(4))) float f32x4;

// ZN_SCALE^2 = 2 * log2(e) = (1/TEMP)*log2(e), so acc = sim*log2(e) and
// exp(sim) == exp2(acc)  -> single v_exp_f32 per element, no extra mul.
#define ZN_SCALE 1.6986436f

__device__ inline unsigned short f2bf_rne(float x) {
  unsigned int u = __float_as_uint(x);
  u += 0x7fffu + ((u >> 16) & 1u);
  return (unsigned short)(u >> 16);
}

// ---------------- normalize: z -> bf16 zn (scaled), store clamped norms ----
__global__ __launch_bounds__(64) void k_normalize(const float* __restrict__ p1,
                                                  const float* __restrict__ p2,
                                                  unsigned short* __restrict__ zn,
                                                  float* __restrict__ norms) {
  int row = blockIdx.x;   // 0..8191
  int lane = threadIdx.x; // 0..63
  const float* src = (row < B_HALF) ? (p1 + (size_t)row * D_DIM)
                                    : (p2 + (size_t)(row - B_HALF) * D_DIM);
  float4 v = *reinterpret_cast<const float4*>(src + lane * 4);
  float ss = v.x * v.x + v.y * v.y + v.z * v.z + v.w * v.w;
#pragma unroll
  for (int m = 1; m < 64; m <<= 1) ss += __shfl_xor(ss, m, 64);
  float nrm = fmaxf(sqrtf(ss), 1e-8f);
  if (lane == 0) norms[row] = nrm;
  float inv = ZN_SCALE / nrm;
  union { unsigned short us[4]; unsigned long long ll; } pk;
  pk.us[0] = f2bf_rne(v.x * inv);
  pk.us[1] = f2bf_rne(v.y * inv);
  pk.us[2] = f2bf_rne(v.z * inv);
  pk.us[3] = f2bf_rne(v.w * inv);
  *reinterpret_cast<unsigned long long*>(zn + (size_t)row * D_DIM + lane * 4) = pk.ll;
}

// ---------------- pos pairs in fp32 (exact), accumulate -2*pos/n ----------
__global__ __launch_bounds__(64) void k_pos(const float* __restrict__ p1,
                                            const float* __restrict__ p2,
                                            const float* __restrict__ norms,
                                            float* __restrict__ out) {
  int i = blockIdx.x;     // 0..4095
  int lane = threadIdx.x; // 0..63
  float4 a = *reinterpret_cast<const float4*>(p1 + (size_t)i * D_DIM + lane * 4);
  float4 b = *reinterpret_cast<const float4*>(p2 + (size_t)i * D_DIM + lane * 4);
  float d = a.x * b.x + a.y * b.y + a.z * b.z + a.w * b.w;
#pragma unroll
  for (int m = 1; m < 64; m <<= 1) d += __shfl_xor(d, m, 64);
  if (lane == 0) {
    float pos = d / (norms[i] * norms[i + B_HALF]) * 2.0f; // 1/TEMP = 2
    atomicAdd(out, -2.0f * pos / (float)N_TOT);
  }
}

// ---------------- fused GEMM + exp row-sum (excl. diagonal) ----------------
// A tile (BM x 256, full K) hoisted in LDS once; B tile (BN x 64) per K-step.
// XOR swizzle (c8 ^= row&7) on both write and read kills stride bank conflicts.
__global__ __launch_bounds__(256) void k_simlse(const unsigned short* __restrict__ zn,
                                                float* __restrict__ rowsum) {
  __shared__ __align__(16) char A_s[BM * 256 * 2]; // 64 KB, row stride 512B
  __shared__ __align__(16) char B_s[BN * 64 * 2];  // 16 KB, row stride 128B

  int bid = blockIdx.x;
  int rt = bid >> 3;   // 64 row tiles
  int cs = bid & 7;    // 8 col chunks
  int rowbase = rt * BM;
  int colchunk = cs * CHUNK;

  int tid = threadIdx.x;
  int lane = tid & 63;
  int wid = tid >> 6; // 0..3
  int wm = wid >> 1;  // 0..1
  int wn = wid & 1;   // 0..1

  // Stage A: 128 rows x 256 K bf16 = 64KB; 256 thr x 16 chunks x 16B
#pragma unroll
  for (int i = 0; i < 16; ++i) {
    int q = tid + 256 * i;
    int row = q >> 5, c8 = q & 31;
    ushort8 v = *reinterpret_cast<const ushort8*>(zn + (size_t)(rowbase + row) * D_DIM + c8 * 8);
    *reinterpret_cast<ushort8*>(A_s + row * 512 + ((c8 ^ (row & 7)) << 4)) = v;
  }

  float psum[4][4]; // [m][r] per-row exp partials
#pragma unroll
  for (int m = 0; m < 4; ++m)
#pragma unroll
    for (int r = 0; r < 4; ++r) psum[m][r] = 0.0f;

  for (int ct = 0; ct < CHUNK / BN; ++ct) {
    int colbase = colchunk + ct * BN;
    f32x4 acc[4][4];
#pragma unroll
    for (int m = 0; m < 4; ++m)
#pragma unroll
      for (int n = 0; n < 4; ++n) acc[m][n] = (f32x4){0.f, 0.f, 0.f, 0.f};

    for (int ks = 0; ks < 4; ++ks) {
      __syncthreads();
      // stage B: BN rows x 64 K = 16KB; 256 thr x 4 x 16B
#pragma unroll
      for (int i = 0; i < 4; ++i) {
        int q = tid + 256 * i;
        int row = q >> 3, c8 = q & 7;
        ushort8 v = *reinterpret_cast<const ushort8*>(
            zn + (size_t)(colbase + row) * D_DIM + ks * 64 + c8 * 8);
        *reinterpret_cast<ushort8*>(B_s + row * 128 + ((c8 ^ (row & 7)) << 4)) = v;
      }
      __syncthreads();
#pragma unroll
      for (int kk = 0; kk < 2; ++kk) {
        short8 af[4], bf[4];
#pragma unroll
        for (int m = 0; m < 4; ++m) {
          int row = wm * 64 + m * 16 + (lane & 15);
          int c8 = ks * 8 + kk * 4 + (lane >> 4);
          af[m] = *reinterpret_cast<const short8*>(A_s + row * 512 + ((c8 ^ (row & 7)) << 4));
        }
#pragma unroll
        for (int n = 0; n < 4; ++n) {
          int row = wn * 64 + n * 16 + (lane & 15);
          int c8 = kk * 4 + (lane >> 4);
          bf[n] = *reinterpret_cast<const short8*>(B_s + row * 128 + ((c8 ^ (row & 7)) << 4));
        }
#pragma unroll
        for (int m = 0; m < 4; ++m)
#pragma unroll
          for (int n = 0; n < 4; ++n)
            acc[m][n] = __builtin_amdgcn_mfma_f32_16x16x32_bf16(af[m], bf[n], acc[m][n], 0, 0, 0);
      }
    }

    // exp2 and accumulate per-row partials; mask diagonal
#pragma unroll
    for (int m = 0; m < 4; ++m) {
      int row_g = rowbase + wm * 64 + m * 16 + (lane >> 4) * 4;
#pragma unroll
      for (int n = 0; n < 4; ++n) {
        int col_g = colbase + wn * 64 + n * 16 + (lane & 15);
#pragma unroll
        for (int r = 0; r < 4; ++r) {
          float e = exp2f(acc[m][n][r]);
          e = (row_g + r == col_g) ? 0.0f : e;
          psum[m][r] += e;
        }
      }
    }
  }

  // reduce over the 16 col-lanes of each group, then one atomic per row
#pragma unroll
  for (int m = 0; m < 4; ++m)
#pragma unroll
    for (int r = 0; r < 4; ++r) {
      float s = psum[m][r];
      s += __shfl_xor(s, 1, 64);
      s += __shfl_xor(s, 2, 64);
      s += __shfl_xor(s, 4, 64);
      s += __shfl_xor(s, 8, 64);
      if ((lane & 15) == 0) {
        int row_g = rowbase + wm * 64 + m * 16 + (lane >> 4) * 4 + r;
        atomicAdd(&rowsum[row_g], s);
      }
    }
}

// ---------------- final: loss += sum(log(rowsum)) / n ----------------------
__global__ __launch_bounds__(256) void k_lse(const float* __restrict__ rowsum,
                                             float* __restrict__ out) {
  int i = blockIdx.x * 256 + threadIdx.x;
  float v = logf(rowsum[i]);
#pragma unroll
  for (int m = 1; m < 64; m <<= 1) v += __shfl_xor(v, m, 64);
  __shared__ float red[4];
  if ((threadIdx.x & 63) == 0) red[threadIdx.x >> 6] = v;
  __syncthreads();
  if (threadIdx.x == 0) {
    float t = red[0] + red[1] + red[2] + red[3];
    atomicAdd(out, t * (1.0f / (float)N_TOT));
  }
}

extern "C" void kernel_launch(void* const* d_in, const int* in_sizes, int n_in,
                              void* d_out, int out_size, void* d_ws, size_t ws_size,
                              hipStream_t stream) {
  const float* p1 = (const float*)d_in[0];
  const float* p2 = (const float*)d_in[1];
  float* out = (float*)d_out;
  char* ws = (char*)d_ws;

  unsigned short* zn = (unsigned short*)ws;                        // 4 MB
  float* norms = (float*)(ws + (size_t)N_TOT * D_DIM * 2);         // 32 KB
  float* rowsum = norms + N_TOT;                                   // 32 KB

  hipMemsetAsync(out, 0, sizeof(float), stream);
  hipMemsetAsync(rowsum, 0, N_TOT * sizeof(float), stream);

  k_normalize<<<N_TOT, 64, 0, stream>>>(p1, p2, zn, norms);
  k_pos<<<B_HALF, 64, 0, stream>>>(p1, p2, norms, out);
  k_simlse<<<NRT * NCS, 256, 0, stream>>>(zn, rowsum);
  k_lse<<<N_TOT / 256, 256, 0, stream>>>(rowsum, out);
}

// Round 2
// 102.618 us; speedup vs baseline: 1.2194x; 1.2194x over previous
//
#include <hip/hip_runtime.h>
#include <hip/hip_bf16.h>

#define N_TOT 8192
#define B_HALF 4096
#define D_DIM 256
#define BM 128
#define CHUNK 1024
#define NRT (N_TOT / BM)     // 64 row tiles
#define NCS (N_TOT / CHUNK)  // 8 col chunks

typedef __attribute__((ext_vector_type(8))) short short8;
typedef __attribute__((ext_vector_type(4))) float f32x4;

// ZN_SCALE^2 = (1/TEMP)*log2(e) = 2*log2(e): acc = sim*log2(e), exp(sim)=exp2(acc)
#define ZN_SCALE 1.6986436f

__device__ inline unsigned short f2bf_rne(float x) {
  unsigned int u = __float_as_uint(x);
  u += 0x7fffu + ((u >> 16) & 1u);
  return (unsigned short)(u >> 16);
}
__device__ inline float bf2f(unsigned short u) {
  return __uint_as_float(((unsigned int)u) << 16);
}

// global->LDS direct (16B/lane). Dest must be wave-uniform; HW adds lane*16.
typedef __attribute__((address_space(3))) void lds_void;
typedef __attribute__((address_space(1))) const void glb_void;
__device__ __forceinline__ void gld16(const void* g, void* l) {
  __builtin_amdgcn_global_load_lds((glb_void*)g, (lds_void*)l, 16, 0, 0);
}

// ---- normalize + pos: z -> bf16 zn (scaled), self = sum(zbf16^2), pos term --
__global__ __launch_bounds__(64) void k_norm(const float* __restrict__ p1,
                                             const float* __restrict__ p2,
                                             unsigned short* __restrict__ zn,
                                             float* __restrict__ self,
                                             float* __restrict__ out) {
  int i = blockIdx.x;     // 0..4095 (row pair)
  int lane = threadIdx.x; // 0..63
  float4 a = *reinterpret_cast<const float4*>(p1 + (size_t)i * D_DIM + lane * 4);
  float4 b = *reinterpret_cast<const float4*>(p2 + (size_t)i * D_DIM + lane * 4);
  float ssa = a.x * a.x + a.y * a.y + a.z * a.z + a.w * a.w;
  float ssb = b.x * b.x + b.y * b.y + b.z * b.z + b.w * b.w;
  float d = a.x * b.x + a.y * b.y + a.z * b.z + a.w * b.w;
#pragma unroll
  for (int m = 1; m < 64; m <<= 1) {
    ssa += __shfl_xor(ssa, m, 64);
    ssb += __shfl_xor(ssb, m, 64);
    d += __shfl_xor(d, m, 64);
  }
  float na = fmaxf(sqrtf(ssa), 1e-8f);
  float nb = fmaxf(sqrtf(ssb), 1e-8f);
  float ia = ZN_SCALE / na, ib = ZN_SCALE / nb;

  union { unsigned short us[4]; unsigned long long ll; } pa, pb;
  pa.us[0] = f2bf_rne(a.x * ia); pa.us[1] = f2bf_rne(a.y * ia);
  pa.us[2] = f2bf_rne(a.z * ia); pa.us[3] = f2bf_rne(a.w * ia);
  pb.us[0] = f2bf_rne(b.x * ib); pb.us[1] = f2bf_rne(b.y * ib);
  pb.us[2] = f2bf_rne(b.z * ib); pb.us[3] = f2bf_rne(b.w * ib);
  *reinterpret_cast<unsigned long long*>(zn + (size_t)i * D_DIM + lane * 4) = pa.ll;
  *reinterpret_cast<unsigned long long*>(zn + (size_t)(i + B_HALF) * D_DIM + lane * 4) = pb.ll;

  // self-similarity in log2 domain: sum of packed bf16 values squared
  float sqa = 0.f, sqb = 0.f;
#pragma unroll
  for (int k = 0; k < 4; ++k) {
    float va = bf2f(pa.us[k]), vb = bf2f(pb.us[k]);
    sqa += va * va; sqb += vb * vb;
  }
#pragma unroll
  for (int m = 1; m < 64; m <<= 1) {
    sqa += __shfl_xor(sqa, m, 64);
    sqb += __shfl_xor(sqb, m, 64);
  }
  if (lane == 0) {
    self[i] = sqa;
    self[i + B_HALF] = sqb;
    // pos = 2*d/(na*nb); loss contribution = -2*pos/n
    atomicAdd(out, -4.0f * d / (na * nb) * (1.0f / (float)N_TOT));
  }
}

// ---- fused GEMM + exp row-sum. A frags in regs; B full-K half-tiles dbuf'd --
__global__ __launch_bounds__(256, 2) void k_simlse(const unsigned short* __restrict__ zn,
                                                   float* __restrict__ rowsum) {
  __shared__ __align__(16) char S[65536]; // A bounce (64KB) then B dbuf 2x32KB

  const int bid = blockIdx.x;
  const int rt = bid >> 3;  // 64 row tiles
  const int cs = bid & 7;   // 8 col chunks
  const int rowbase = rt * BM;
  const int colchunk = cs * CHUNK;

  const int tid = threadIdx.x;
  const int lane = tid & 63;
  const int wid = tid >> 6; // 0..3
  const int wm = wid >> 1;  // row half
  const int wn = wid & 1;   // col half (32 of 64)

  // ---- stage A: 128 rows x 256 K, swizzled via pre-swizzled global source --
#pragma unroll
  for (int i = 0; i < 16; ++i) {
    int q = i * 256 + tid;
    int row = q >> 5, c8s = q & 31;
    gld16(zn + (((size_t)(rowbase + row)) << 8) + ((c8s ^ (row & 7)) << 3),
          S + i * 4096 + wid * 1024);
  }
  __syncthreads();

  // ---- A fragments -> registers (row-invariant for whole block) ----
  short8 af[4][8]; // [m][k8], 128 VGPRs
#pragma unroll
  for (int m = 0; m < 4; ++m) {
    int row = wm * 64 + m * 16 + (lane & 15);
#pragma unroll
    for (int k8 = 0; k8 < 8; ++k8) {
      int c8 = k8 * 4 + (lane >> 4);
      af[m][k8] = *reinterpret_cast<const short8*>(S + row * 512 + ((c8 ^ (row & 7)) << 4));
    }
  }
  __syncthreads();

  // ---- prologue: stage B half-tile 0 (64 cols x 256 K = 32 KB) into buf0 ---
#pragma unroll
  for (int i = 0; i < 8; ++i) {
    int q = i * 256 + tid;
    int row = q >> 5, c8s = q & 31;
    gld16(zn + (((size_t)(colchunk + row)) << 8) + ((c8s ^ (row & 7)) << 3),
          S + i * 4096 + wid * 1024);
  }
  __syncthreads();

  float psum[4][4] = {}; // [m][r] per-row exp partials

  for (int ht = 0; ht < CHUNK / 64; ++ht) {
    char* Bc = S + (ht & 1) * 32768;
    // prefetch next half-tile into the other buffer (overlaps with MFMA)
    if (ht < CHUNK / 64 - 1) {
      char* Bn = S + ((ht + 1) & 1) * 32768;
      int colb = colchunk + (ht + 1) * 64;
#pragma unroll
      for (int i = 0; i < 8; ++i) {
        int q = i * 256 + tid;
        int row = q >> 5, c8s = q & 31;
        gld16(zn + (((size_t)(colb + row)) << 8) + ((c8s ^ (row & 7)) << 3),
              Bn + i * 4096 + wid * 1024);
      }
    }

    f32x4 acc[4][2];
#pragma unroll
    for (int m = 0; m < 4; ++m)
#pragma unroll
      for (int n = 0; n < 2; ++n) acc[m][n] = (f32x4){0.f, 0.f, 0.f, 0.f};

#pragma unroll
    for (int k8 = 0; k8 < 8; ++k8) {
      short8 bf[2];
#pragma unroll
      for (int n = 0; n < 2; ++n) {
        int crow = wn * 32 + n * 16 + (lane & 15);
        int c8 = k8 * 4 + (lane >> 4);
        bf[n] = *reinterpret_cast<const short8*>(Bc + crow * 512 + ((c8 ^ (crow & 7)) << 4));
      }
#pragma unroll
      for (int m = 0; m < 4; ++m)
#pragma unroll
        for (int n = 0; n < 2; ++n)
          acc[m][n] = __builtin_amdgcn_mfma_f32_16x16x32_bf16(af[m][k8], bf[n], acc[m][n], 0, 0, 0);
    }

    __syncthreads(); // bf reads done for all waves; next-tile stage drained

    // epilogue (regs only, overlaps other waves' next-tile work)
#pragma unroll
    for (int m = 0; m < 4; ++m)
#pragma unroll
      for (int n = 0; n < 2; ++n)
#pragma unroll
        for (int r = 0; r < 4; ++r)
          psum[m][r] += __builtin_amdgcn_exp2f(acc[m][n][r]);
  }

  // reduce across the 16 col-lanes, one atomic per (row, wave)
#pragma unroll
  for (int m = 0; m < 4; ++m)
#pragma unroll
    for (int r = 0; r < 4; ++r) {
      float s = psum[m][r];
      s += __shfl_xor(s, 1, 64);
      s += __shfl_xor(s, 2, 64);
      s += __shfl_xor(s, 4, 64);
      s += __shfl_xor(s, 8, 64);
      if ((lane & 15) == 0) {
        int row_g = rowbase + wm * 64 + m * 16 + (lane >> 4) * 4 + r;
        atomicAdd(&rowsum[row_g], s);
      }
    }
}

// ---- final: loss += sum(log(rowsum - exp2(self))) / n ----------------------
__global__ __launch_bounds__(256) void k_lse(const float* __restrict__ rowsum,
                                             const float* __restrict__ self,
                                             float* __restrict__ out) {
  int i = blockIdx.x * 256 + threadIdx.x;
  float rs = rowsum[i] - __builtin_amdgcn_exp2f(self[i]);
  float v = logf(rs);
#pragma unroll
  for (int m = 1; m < 64; m <<= 1) v += __shfl_xor(v, m, 64);
  __shared__ float red[4];
  if ((threadIdx.x & 63) == 0) red[threadIdx.x >> 6] = v;
  __syncthreads();
  if (threadIdx.x == 0) {
    float t = red[0] + red[1] + red[2] + red[3];
    atomicAdd(out, t * (1.0f / (float)N_TOT));
  }
}

extern "C" void kernel_launch(void* const* d_in, const int* in_sizes, int n_in,
                              void* d_out, int out_size, void* d_ws, size_t ws_size,
                              hipStream_t stream) {
  const float* p1 = (const float*)d_in[0];
  const float* p2 = (const float*)d_in[1];
  float* out = (float*)d_out;
  char* ws = (char*)d_ws;

  unsigned short* zn = (unsigned short*)ws;                      // 4 MB
  float* self = (float*)(ws + (size_t)N_TOT * D_DIM * 2);        // 32 KB
  float* rowsum = self + N_TOT;                                  // 32 KB

  hipMemsetAsync(out, 0, sizeof(float), stream);
  hipMemsetAsync(rowsum, 0, N_TOT * sizeof(float), stream);

  k_norm<<<B_HALF, 64, 0, stream>>>(p1, p2, zn, self, out);
  k_simlse<<<NRT * NCS, 256, 0, stream>>>(zn, rowsum);
  k_lse<<<N_TOT / 256, 256, 0, stream>>>(rowsum, self, out);
}

// Round 3
// 55.582 us; speedup vs baseline: 2.2513x; 1.8462x over previous
//
#include <hip/hip_runtime.h>
#include <hip/hip_bf16.h>

#define N_TOT 8192
#define B_HALF 4096
#define D_DIM 256
#define BM 128
#define CHUNK 1024
#define NRT (N_TOT / BM)     // 64 row tiles
#define NCS (N_TOT / CHUNK)  // 8 col chunks

typedef __attribute__((ext_vector_type(8))) short short8;
typedef __attribute__((ext_vector_type(4))) float f32x4;

// ZN_SCALE^2 = (1/TEMP)*log2(e) = 2*log2(e): acc = sim*log2(e), exp(sim)=exp2(acc)
#define ZN_SCALE 1.6986436f

__device__ inline unsigned short f2bf_rne(float x) {
  unsigned int u = __float_as_uint(x);
  u += 0x7fffu + ((u >> 16) & 1u);
  return (unsigned short)(u >> 16);
}
__device__ inline float bf2f(unsigned short u) {
  return __uint_as_float(((unsigned int)u) << 16);
}

// global->LDS direct (16B/lane). Dest must be wave-uniform; HW adds lane*16.
typedef __attribute__((address_space(3))) void lds_void;
typedef __attribute__((address_space(1))) const void glb_void;
__device__ __forceinline__ void gld16(const void* g, void* l) {
  __builtin_amdgcn_global_load_lds((glb_void*)g, (lds_void*)l, 16, 0, 0);
}

// ---- normalize + pos: 4 pairs/block, pos partial -> plain store (no atomics)
__global__ __launch_bounds__(256) void k_norm(const float* __restrict__ p1,
                                              const float* __restrict__ p2,
                                              unsigned short* __restrict__ zn,
                                              float* __restrict__ self,
                                              float* __restrict__ partials) {
  int tid = threadIdx.x;
  int lane = tid & 63;
  int w = tid >> 6;                 // wave 0..3
  int i = blockIdx.x * 4 + w;       // pair index 0..4095
  float4 a = *reinterpret_cast<const float4*>(p1 + (size_t)i * D_DIM + lane * 4);
  float4 b = *reinterpret_cast<const float4*>(p2 + (size_t)i * D_DIM + lane * 4);
  float ssa = a.x * a.x + a.y * a.y + a.z * a.z + a.w * a.w;
  float ssb = b.x * b.x + b.y * b.y + b.z * b.z + b.w * b.w;
  float d = a.x * b.x + a.y * b.y + a.z * b.z + a.w * b.w;
#pragma unroll
  for (int m = 1; m < 64; m <<= 1) {
    ssa += __shfl_xor(ssa, m, 64);
    ssb += __shfl_xor(ssb, m, 64);
    d += __shfl_xor(d, m, 64);
  }
  float na = fmaxf(sqrtf(ssa), 1e-8f);
  float nb = fmaxf(sqrtf(ssb), 1e-8f);
  float ia = ZN_SCALE / na, ib = ZN_SCALE / nb;

  union { unsigned short us[4]; unsigned long long ll; } pa, pb;
  pa.us[0] = f2bf_rne(a.x * ia); pa.us[1] = f2bf_rne(a.y * ia);
  pa.us[2] = f2bf_rne(a.z * ia); pa.us[3] = f2bf_rne(a.w * ia);
  pb.us[0] = f2bf_rne(b.x * ib); pb.us[1] = f2bf_rne(b.y * ib);
  pb.us[2] = f2bf_rne(b.z * ib); pb.us[3] = f2bf_rne(b.w * ib);
  *reinterpret_cast<unsigned long long*>(zn + (size_t)i * D_DIM + lane * 4) = pa.ll;
  *reinterpret_cast<unsigned long long*>(zn + (size_t)(i + B_HALF) * D_DIM + lane * 4) = pb.ll;

  // self-similarity in log2 domain: sum of packed bf16 values squared
  float sqa = 0.f, sqb = 0.f;
#pragma unroll
  for (int k = 0; k < 4; ++k) {
    float va = bf2f(pa.us[k]), vb = bf2f(pb.us[k]);
    sqa += va * va; sqb += vb * vb;
  }
#pragma unroll
  for (int m = 1; m < 64; m <<= 1) {
    sqa += __shfl_xor(sqa, m, 64);
    sqb += __shfl_xor(sqb, m, 64);
  }
  __shared__ float red[4];
  if (lane == 0) {
    self[i] = sqa;
    self[i + B_HALF] = sqb;
    // pos = 2*d/(na*nb); per-pair loss contribution = -2*pos/n
    red[w] = -4.0f * d / (na * nb) * (1.0f / (float)N_TOT);
  }
  __syncthreads();
  if (tid == 0) partials[blockIdx.x] = red[0] + red[1] + red[2] + red[3];
}

// ---- fused GEMM + exp row-sum. A frags in regs; B full-K half-tiles dbuf'd --
__global__ __launch_bounds__(256, 2) void k_simlse(const unsigned short* __restrict__ zn,
                                                   float* __restrict__ rowsum) {
  __shared__ __align__(16) char S[65536]; // A bounce (64KB) then B dbuf 2x32KB

  const int bid = blockIdx.x;
  const int rt = bid >> 3;  // 64 row tiles
  const int cs = bid & 7;   // 8 col chunks
  const int rowbase = rt * BM;
  const int colchunk = cs * CHUNK;

  const int tid = threadIdx.x;
  const int lane = tid & 63;
  const int wid = tid >> 6; // 0..3
  const int wm = wid >> 1;  // row half
  const int wn = wid & 1;   // col half (32 of 64)

  // ---- stage A: 128 rows x 256 K, swizzled via pre-swizzled global source --
#pragma unroll
  for (int i = 0; i < 16; ++i) {
    int q = i * 256 + tid;
    int row = q >> 5, c8s = q & 31;
    gld16(zn + (((size_t)(rowbase + row)) << 8) + ((c8s ^ (row & 7)) << 3),
          S + i * 4096 + wid * 1024);
  }
  __syncthreads();

  // ---- A fragments -> registers (row-invariant for whole block) ----
  short8 af[4][8]; // [m][k8], 128 VGPRs
#pragma unroll
  for (int m = 0; m < 4; ++m) {
    int row = wm * 64 + m * 16 + (lane & 15);
#pragma unroll
    for (int k8 = 0; k8 < 8; ++k8) {
      int c8 = k8 * 4 + (lane >> 4);
      af[m][k8] = *reinterpret_cast<const short8*>(S + row * 512 + ((c8 ^ (row & 7)) << 4));
    }
  }
  __syncthreads();

  // ---- prologue: stage B half-tile 0 (64 cols x 256 K = 32 KB) into buf0 ---
#pragma unroll
  for (int i = 0; i < 8; ++i) {
    int q = i * 256 + tid;
    int row = q >> 5, c8s = q & 31;
    gld16(zn + (((size_t)(colchunk + row)) << 8) + ((c8s ^ (row & 7)) << 3),
          S + i * 4096 + wid * 1024);
  }
  __syncthreads();

  float psum[4][4] = {}; // [m][r] per-row exp partials

  for (int ht = 0; ht < CHUNK / 64; ++ht) {
    char* Bc = S + (ht & 1) * 32768;
    // prefetch next half-tile into the other buffer (overlaps with MFMA)
    if (ht < CHUNK / 64 - 1) {
      char* Bn = S + ((ht + 1) & 1) * 32768;
      int colb = colchunk + (ht + 1) * 64;
#pragma unroll
      for (int i = 0; i < 8; ++i) {
        int q = i * 256 + tid;
        int row = q >> 5, c8s = q & 31;
        gld16(zn + (((size_t)(colb + row)) << 8) + ((c8s ^ (row & 7)) << 3),
              Bn + i * 4096 + wid * 1024);
      }
    }

    f32x4 acc[4][2];
#pragma unroll
    for (int m = 0; m < 4; ++m)
#pragma unroll
      for (int n = 0; n < 2; ++n) acc[m][n] = (f32x4){0.f, 0.f, 0.f, 0.f};

#pragma unroll
    for (int k8 = 0; k8 < 8; ++k8) {
      short8 bf[2];
#pragma unroll
      for (int n = 0; n < 2; ++n) {
        int crow = wn * 32 + n * 16 + (lane & 15);
        int c8 = k8 * 4 + (lane >> 4);
        bf[n] = *reinterpret_cast<const short8*>(Bc + crow * 512 + ((c8 ^ (crow & 7)) << 4));
      }
#pragma unroll
      for (int m = 0; m < 4; ++m)
#pragma unroll
        for (int n = 0; n < 2; ++n)
          acc[m][n] = __builtin_amdgcn_mfma_f32_16x16x32_bf16(af[m][k8], bf[n], acc[m][n], 0, 0, 0);
    }

    __syncthreads(); // bf reads done for all waves; next-tile stage drained

    // epilogue (regs only, overlaps other waves' next-tile work)
#pragma unroll
    for (int m = 0; m < 4; ++m)
#pragma unroll
      for (int n = 0; n < 2; ++n)
#pragma unroll
        for (int r = 0; r < 4; ++r)
          psum[m][r] += __builtin_amdgcn_exp2f(acc[m][n][r]);
  }

  // reduce across the 16 col-lanes, one atomic per (row, wave) — distinct addrs
#pragma unroll
  for (int m = 0; m < 4; ++m)
#pragma unroll
    for (int r = 0; r < 4; ++r) {
      float s = psum[m][r];
      s += __shfl_xor(s, 1, 64);
      s += __shfl_xor(s, 2, 64);
      s += __shfl_xor(s, 4, 64);
      s += __shfl_xor(s, 8, 64);
      if ((lane & 15) == 0) {
        int row_g = rowbase + wm * 64 + m * 16 + (lane >> 4) * 4 + r;
        atomicAdd(&rowsum[row_g], s);
      }
    }
}

// ---- final: loss += sum(log(rowsum - exp2(self)))/n + sum(partials) --------
__global__ __launch_bounds__(256) void k_lse(const float* __restrict__ rowsum,
                                             const float* __restrict__ self,
                                             const float* __restrict__ partials,
                                             float* __restrict__ out) {
  int tid = threadIdx.x;
  int i = blockIdx.x * 256 + tid;
  float rs = rowsum[i] - __builtin_amdgcn_exp2f(self[i]);
  float v = logf(rs) * (1.0f / (float)N_TOT);
  if (tid < 32) v += partials[blockIdx.x * 32 + tid]; // 1024 partials / 32 blocks
#pragma unroll
  for (int m = 1; m < 64; m <<= 1) v += __shfl_xor(v, m, 64);
  __shared__ float red[4];
  if ((tid & 63) == 0) red[tid >> 6] = v;
  __syncthreads();
  if (tid == 0) {
    float t = red[0] + red[1] + red[2] + red[3];
    atomicAdd(out, t);
  }
}

extern "C" void kernel_launch(void* const* d_in, const int* in_sizes, int n_in,
                              void* d_out, int out_size, void* d_ws, size_t ws_size,
                              hipStream_t stream) {
  const float* p1 = (const float*)d_in[0];
  const float* p2 = (const float*)d_in[1];
  float* out = (float*)d_out;
  char* ws = (char*)d_ws;

  unsigned short* zn = (unsigned short*)ws;                      // 4 MB
  float* self = (float*)(ws + (size_t)N_TOT * D_DIM * 2);        // 32 KB
  float* rowsum = self + N_TOT;                                  // 32 KB
  float* partials = rowsum + N_TOT;                              // 4 KB

  hipMemsetAsync(out, 0, sizeof(float), stream);
  hipMemsetAsync(rowsum, 0, N_TOT * sizeof(float), stream);

  k_norm<<<B_HALF / 4, 256, 0, stream>>>(p1, p2, zn, self, partials);
  k_simlse<<<NRT * NCS, 256, 0, stream>>>(zn, rowsum);
  k_lse<<<N_TOT / 256, 256, 0, stream>>>(rowsum, self, partials, out);
}

// Round 4
// 48.427 us; speedup vs baseline: 2.5839x; 1.1477x over previous
//
#include <hip/hip_runtime.h>
#include <hip/hip_bf16.h>

#define N_TOT 8192
#define B_HALF 4096
#define D_DIM 256
#define BM 128
#define CHUNK 1024
#define NRT (N_TOT / BM)     // 64 row tiles
#define NCS (N_TOT / CHUNK)  // 8 col chunks
#define NHT (CHUNK / 64)     // 16 column half-tiles per block

typedef __attribute__((ext_vector_type(8))) short short8;
typedef __attribute__((ext_vector_type(4))) float f32x4;

// ZN_SCALE^2 = (1/TEMP)*log2(e) = 2*log2(e): acc = sim*log2(e), exp(sim)=exp2(acc)
#define ZN_SCALE 1.6986436f
#define LN2 0.69314718056f

__device__ inline unsigned short f2bf_rne(float x) {
  unsigned int u = __float_as_uint(x);
  u += 0x7fffu + ((u >> 16) & 1u);
  return (unsigned short)(u >> 16);
}
__device__ inline float bf2f(unsigned short u) {
  return __uint_as_float(((unsigned int)u) << 16);
}

// global->LDS direct (16B/lane). Dest must be wave-uniform; HW adds lane*16.
typedef __attribute__((address_space(3))) void lds_void;
typedef __attribute__((address_space(1))) const void glb_void;
__device__ __forceinline__ void gld16(const void* g, void* l) {
  __builtin_amdgcn_global_load_lds((glb_void*)g, (lds_void*)l, 16, 0, 0);
}

// ---- normalize + pos partials + rowsum zeroing ----------------------------
__global__ __launch_bounds__(256) void k_norm(const float* __restrict__ p1,
                                              const float* __restrict__ p2,
                                              unsigned short* __restrict__ zn,
                                              float* __restrict__ self,
                                              float* __restrict__ partials,
                                              float* __restrict__ rowsum) {
  int tid = threadIdx.x;
  int lane = tid & 63;
  int w = tid >> 6;                 // wave 0..3
  int i = blockIdx.x * 4 + w;       // pair index 0..4095
  if (blockIdx.x < 32) rowsum[blockIdx.x * 256 + tid] = 0.0f; // zero for k_simlse
  float4 a = *reinterpret_cast<const float4*>(p1 + (size_t)i * D_DIM + lane * 4);
  float4 b = *reinterpret_cast<const float4*>(p2 + (size_t)i * D_DIM + lane * 4);
  float ssa = a.x * a.x + a.y * a.y + a.z * a.z + a.w * a.w;
  float ssb = b.x * b.x + b.y * b.y + b.z * b.z + b.w * b.w;
  float d = a.x * b.x + a.y * b.y + a.z * b.z + a.w * b.w;
#pragma unroll
  for (int m = 1; m < 64; m <<= 1) {
    ssa += __shfl_xor(ssa, m, 64);
    ssb += __shfl_xor(ssb, m, 64);
    d += __shfl_xor(d, m, 64);
  }
  float na = fmaxf(sqrtf(ssa), 1e-8f);
  float nb = fmaxf(sqrtf(ssb), 1e-8f);
  float ia = ZN_SCALE / na, ib = ZN_SCALE / nb;

  union { unsigned short us[4]; unsigned long long ll; } pa, pb;
  pa.us[0] = f2bf_rne(a.x * ia); pa.us[1] = f2bf_rne(a.y * ia);
  pa.us[2] = f2bf_rne(a.z * ia); pa.us[3] = f2bf_rne(a.w * ia);
  pb.us[0] = f2bf_rne(b.x * ib); pb.us[1] = f2bf_rne(b.y * ib);
  pb.us[2] = f2bf_rne(b.z * ib); pb.us[3] = f2bf_rne(b.w * ib);
  *reinterpret_cast<unsigned long long*>(zn + (size_t)i * D_DIM + lane * 4) = pa.ll;
  *reinterpret_cast<unsigned long long*>(zn + (size_t)(i + B_HALF) * D_DIM + lane * 4) = pb.ll;

  float sqa = 0.f, sqb = 0.f;
#pragma unroll
  for (int k = 0; k < 4; ++k) {
    float va = bf2f(pa.us[k]), vb = bf2f(pb.us[k]);
    sqa += va * va; sqb += vb * vb;
  }
#pragma unroll
  for (int m = 1; m < 64; m <<= 1) {
    sqa += __shfl_xor(sqa, m, 64);
    sqb += __shfl_xor(sqb, m, 64);
  }
  __shared__ float red[4];
  if (lane == 0) {
    self[i] = sqa;
    self[i + B_HALF] = sqb;
    red[w] = -4.0f * d / (na * nb) * (1.0f / (float)N_TOT);
  }
  __syncthreads();
  if (tid == 0) partials[blockIdx.x] = red[0] + red[1] + red[2] + red[3];
}

// ---- fused GEMM + exp row-sum; 4-phase schedule, counted vmcnt, setprio ----
__global__ __launch_bounds__(256, 2) void k_simlse(const unsigned short* __restrict__ zn,
                                                   float* __restrict__ rowsum) {
  __shared__ __align__(16) char S[65536]; // A bounce (64KB) then B dbuf 2x32KB

  const int bid = blockIdx.x;
  const int rt = bid >> 3;
  const int cs = bid & 7;
  const int rowbase = rt * BM;
  const int colchunk = cs * CHUNK;

  const int tid = threadIdx.x;
  const int lane = tid & 63;
  const int wid = tid >> 6;
  const int wm = wid >> 1;  // row half
  const int wn = wid & 1;   // col half (32 of 64)
  const int hi = lane >> 4; // k-subgroup 0..3
  const char* zb = (const char*)zn;

  // ---- stage A: 128 rows x 256 K, swizzled via pre-swizzled global source --
#pragma unroll
  for (int i = 0; i < 16; ++i) {
    int q = i * 256 + tid;
    int row = q >> 5, c8s = q & 31;
    gld16(zb + (((size_t)(rowbase + row)) << 9) + ((size_t)(c8s ^ (row & 7)) << 4),
          S + i * 4096 + wid * 1024);
  }
  __syncthreads();

  // ---- A fragments -> registers (block-invariant) ----
  short8 af[4][8]; // [m][k8], 128 VGPRs
#pragma unroll
  for (int m = 0; m < 4; ++m) {
    int row = wm * 64 + m * 16 + (lane & 15);
#pragma unroll
    for (int k8 = 0; k8 < 8; ++k8) {
      int c8 = k8 * 4 + hi;
      af[m][k8] = *reinterpret_cast<const short8*>(S + row * 512 + ((c8 ^ (row & 7)) << 4));
    }
  }
  __syncthreads();

  // per-thread swizzled global base for B staging (thread tid loads i*4096+tid*16)
  const size_t swz = (size_t)((tid & 31) ^ ((tid >> 5) & 7)) << 4;
  const char* g0 = zb + (((size_t)(colchunk + (tid >> 5))) << 9) + swz;

  // ---- prologue: issue half-tile 0's 8 loads into buf0 ----
#pragma unroll
  for (int i = 0; i < 8; ++i) gld16(g0 + i * 4096, S + i * 4096 + wid * 1024);

  // B fragment read coords (per thread, compile-time per n)
  const int crow0 = wn * 32 + (lane & 15);
  const int crow1 = crow0 + 16;
  const int cr7_0 = crow0 & 7, cr7_1 = crow1 & 7;

  float psum[4][4] = {}; // [m][r] per-row exp partials

  for (int ht = 0; ht < NHT; ++ht) {
    char* Bc = S + (ht & 1) * 32768;
    char* Bn = S + ((ht + 1) & 1) * 32768;
    const char* gsrc = g0 + (size_t)(ht + 1) * 32768;
    const bool last = (ht == NHT - 1);

    // issue first 2 of next tile's loads, then counted wait: current tile's
    // 8 loads (issued last iteration) complete; the 2 new stay in flight.
    if (!last) {
      gld16(gsrc, Bn + wid * 1024);
      gld16(gsrc + 4096, Bn + 4096 + wid * 1024);
      asm volatile("s_waitcnt vmcnt(2)" ::: "memory");
    } else {
      asm volatile("s_waitcnt vmcnt(0)" ::: "memory");
    }
    __builtin_amdgcn_s_barrier();
    __builtin_amdgcn_sched_barrier(0);

    f32x4 acc[4][2];
#pragma unroll
    for (int m = 0; m < 4; ++m)
#pragma unroll
      for (int n = 0; n < 2; ++n) acc[m][n] = (f32x4){0.f, 0.f, 0.f, 0.f};

#pragma unroll
    for (int p = 0; p < 4; ++p) {
      short8 bf0[2], bf1[2]; // [n] for k8 = 2p, 2p+1
      bf0[0] = *reinterpret_cast<const short8*>(Bc + crow0 * 512 + (((p * 8 + hi) ^ cr7_0) << 4));
      bf0[1] = *reinterpret_cast<const short8*>(Bc + crow1 * 512 + (((p * 8 + hi) ^ cr7_1) << 4));
      bf1[0] = *reinterpret_cast<const short8*>(Bc + crow0 * 512 + (((p * 8 + 4 + hi) ^ cr7_0) << 4));
      bf1[1] = *reinterpret_cast<const short8*>(Bc + crow1 * 512 + (((p * 8 + 4 + hi) ^ cr7_1) << 4));
      if (p > 0 && !last) {
        gld16(gsrc + (size_t)(2 * p) * 4096, Bn + (2 * p) * 4096 + wid * 1024);
        gld16(gsrc + (size_t)(2 * p + 1) * 4096, Bn + (2 * p + 1) * 4096 + wid * 1024);
      }
      __builtin_amdgcn_s_setprio(1);
#pragma unroll
      for (int m = 0; m < 4; ++m) {
        acc[m][0] = __builtin_amdgcn_mfma_f32_16x16x32_bf16(af[m][2 * p], bf0[0], acc[m][0], 0, 0, 0);
        acc[m][1] = __builtin_amdgcn_mfma_f32_16x16x32_bf16(af[m][2 * p], bf0[1], acc[m][1], 0, 0, 0);
        acc[m][0] = __builtin_amdgcn_mfma_f32_16x16x32_bf16(af[m][2 * p + 1], bf1[0], acc[m][0], 0, 0, 0);
        acc[m][1] = __builtin_amdgcn_mfma_f32_16x16x32_bf16(af[m][2 * p + 1], bf1[1], acc[m][1], 0, 0, 0);
      }
      __builtin_amdgcn_s_setprio(0);
      __builtin_amdgcn_s_barrier();
      __builtin_amdgcn_sched_barrier(0);
    }

    // epilogue (regs only; other block's waves keep the MFMA pipe fed)
#pragma unroll
    for (int m = 0; m < 4; ++m)
#pragma unroll
      for (int n = 0; n < 2; ++n)
#pragma unroll
        for (int r = 0; r < 4; ++r)
          psum[m][r] += __builtin_amdgcn_exp2f(acc[m][n][r]);
  }

  // reduce across the 16 col-lanes, one atomic per (row, wave) — distinct addrs
#pragma unroll
  for (int m = 0; m < 4; ++m)
#pragma unroll
    for (int r = 0; r < 4; ++r) {
      float s = psum[m][r];
      s += __shfl_xor(s, 1, 64);
      s += __shfl_xor(s, 2, 64);
      s += __shfl_xor(s, 4, 64);
      s += __shfl_xor(s, 8, 64);
      if ((lane & 15) == 0) {
        int row_g = rowbase + wm * 64 + m * 16 + hi * 4 + r;
        atomicAdd(&rowsum[row_g], s);
      }
    }
}

// ---- final: single block, out = sum(log(rowsum-exp2(self)))/n + partials ---
__global__ __launch_bounds__(256) void k_lse(const float* __restrict__ rowsum,
                                             const float* __restrict__ self,
                                             const float* __restrict__ partials,
                                             float* __restrict__ out) {
  int tid = threadIdx.x;
  float l2 = 0.f;
#pragma unroll
  for (int r = 0; r < 32; ++r) {
    int i = r * 256 + tid;
    float rs = rowsum[i] - __builtin_amdgcn_exp2f(self[i]);
    l2 += __builtin_amdgcn_logf(rs); // v_log_f32 = log2
  }
  float v = l2 * (LN2 / (float)N_TOT);
  v += partials[tid] + partials[tid + 256] + partials[tid + 512] + partials[tid + 768];
#pragma unroll
  for (int m = 1; m < 64; m <<= 1) v += __shfl_xor(v, m, 64);
  __shared__ float red[4];
  if ((tid & 63) == 0) red[tid >> 6] = v;
  __syncthreads();
  if (tid == 0) out[0] = red[0] + red[1] + red[2] + red[3];
}

extern "C" void kernel_launch(void* const* d_in, const int* in_sizes, int n_in,
                              void* d_out, int out_size, void* d_ws, size_t ws_size,
                              hipStream_t stream) {
  const float* p1 = (const float*)d_in[0];
  const float* p2 = (const float*)d_in[1];
  float* out = (float*)d_out;
  char* ws = (char*)d_ws;

  unsigned short* zn = (unsigned short*)ws;                      // 4 MB
  float* self = (float*)(ws + (size_t)N_TOT * D_DIM * 2);        // 32 KB
  float* rowsum = self + N_TOT;                                  // 32 KB
  float* partials = rowsum + N_TOT;                              // 4 KB

  k_norm<<<B_HALF / 4, 256, 0, stream>>>(p1, p2, zn, self, partials, rowsum);
  k_simlse<<<NRT * NCS, 256, 0, stream>>>(zn, rowsum);
  k_lse<<<1, 256, 0, stream>>>(rowsum, self, partials, out);
}